// Round 2
// baseline (772.382 us; speedup 1.0000x reference)
//
#include <hip/hip_runtime.h>
#include <hip/hip_bf16.h>
#include <cstdint>

#define PI_F 3.14159265358979323846f

typedef __attribute__((ext_vector_type(8))) short bf16x8;
typedef __attribute__((ext_vector_type(4))) float f32x4;

__device__ __forceinline__ void gload_lds16(const void* g, void* l) {
  __builtin_amdgcn_global_load_lds(
      (const __attribute__((address_space(1))) void*)g,
      (__attribute__((address_space(3))) void*)l, 16, 0, 0);
}

// ---------------------------------------------------------------------------
// prep: feat = [cos(cond), sin(cond)] as bf16; z_new even cols = cond; zero ld
// ---------------------------------------------------------------------------
__global__ __launch_bounds__(256) void prep_feat_kernel(
    const float* __restrict__ z, __hip_bfloat16* __restrict__ feat,
    float* __restrict__ zout, float* __restrict__ logdet)
{
  int idx = blockIdx.x * 256 + threadIdx.x;    // B*512 threads
  int b = idx >> 9, j = idx & 511;
  float2 zz = ((const float2*)z)[idx];         // z[b][2j], z[b][2j+1]
  feat[(size_t)b * 1024 + j]       = __float2bfloat16(cosf(zz.x));
  feat[(size_t)b * 1024 + 512 + j] = __float2bfloat16(sinf(zz.x));
  zout[(size_t)b * 1024 + 2 * j]   = zz.x;
  if (idx < 8192) logdet[idx] = 0.f;
}

// ---------------------------------------------------------------------------
// transpose f32 [R][C] -> bf16 [C][R]   (used for W1)
// ---------------------------------------------------------------------------
__global__ __launch_bounds__(256) void transpose_bf16_kernel(
    const float* __restrict__ src, __hip_bfloat16* __restrict__ dst, int R, int C)
{
  __shared__ float tile[32][33];
  int c0 = blockIdx.x * 32, r0 = blockIdx.y * 32;
  int x = threadIdx.x, y = threadIdx.y;        // 32 x 8
  #pragma unroll
  for (int i = 0; i < 32; i += 8)
    tile[y + i][x] = src[(size_t)(r0 + y + i) * C + c0 + x];
  __syncthreads();
  #pragma unroll
  for (int i = 0; i < 32; i += 8)
    dst[(size_t)(c0 + y + i) * R + r0 + x] = __float2bfloat16(tile[x][y + i]);
}

// ---------------------------------------------------------------------------
// W2 transpose with t-group padding: out[t*32+j][k] = W2[k][t*30+j] (j<30), 0 pad
// out is [16384][1024] bf16.
// ---------------------------------------------------------------------------
__global__ __launch_bounds__(256) void transpose_w2_pad_kernel(
    const float* __restrict__ W2, __hip_bfloat16* __restrict__ dst)
{
  __shared__ float tile[32][33];
  int t = blockIdx.x;                          // 0..511
  int k0 = blockIdx.y * 32;                    // 0..991
  int x = threadIdx.x, y = threadIdx.y;        // 32 x 8
  #pragma unroll
  for (int i = 0; i < 32; i += 8)
    tile[y + i][x] = (x < 30) ? W2[(size_t)(k0 + y + i) * 15360 + t * 30 + x] : 0.f;
  __syncthreads();
  #pragma unroll
  for (int i = 0; i < 32; i += 8)
    dst[(size_t)(t * 32 + y + i) * 1024 + k0 + x] = __float2bfloat16(tile[x][y + i]);
}

// ---------------------------------------------------------------------------
// GEMM1: h = relu(feat @ W1 + b1), M=8192 N=1024 K=1024, out bf16 (unchanged)
// ---------------------------------------------------------------------------
__global__ __launch_bounds__(256, 2) void gemm1_kernel(
    const __hip_bfloat16* __restrict__ A, const __hip_bfloat16* __restrict__ Bt,
    const float* __restrict__ bias, __hip_bfloat16* __restrict__ H)
{
  __shared__ __align__(16) char smem[32768];
  const int tid = threadIdx.x;
  const int lane = tid & 63;
  const int w = tid >> 6;
  const int m0 = blockIdx.x * 128;
  const int n0 = blockIdx.y * 128;
  const int lrow = lane >> 3;
  const int scol = ((lane & 7) ^ lrow) << 4;
  const int fofs0 = ((lane >> 4) << 4) ^ ((lane & 7) << 4);
  const int arow = w * 32 + (lane & 15);
  const int brow = (lane & 15);

  f32x4 acc[2][8];
  #pragma unroll
  for (int i = 0; i < 2; ++i)
    #pragma unroll
    for (int j = 0; j < 8; ++j) acc[i][j] = (f32x4){0.f, 0.f, 0.f, 0.f};

  const char* Abase = (const char*)A + (size_t)(m0 + lrow) * 2048 + scol;
  const char* Bbase = (const char*)Bt + (size_t)(n0 + lrow) * 2048 + scol;

  for (int kt = 0; kt < 16; ++kt) {
    const int k0b = kt * 128;
    __syncthreads();
    #pragma unroll
    for (int i = 0; i < 8; ++i) {
      int c = w + i * 4;
      if (c < 16) gload_lds16(Abase + (size_t)c * 16384 + k0b, smem + c * 1024);
      else        gload_lds16(Bbase + (size_t)(c - 16) * 16384 + k0b,
                              smem + 16384 + (c - 16) * 1024);
    }
    asm volatile("s_waitcnt vmcnt(0)" ::: "memory");
    __syncthreads();
    #pragma unroll
    for (int ks = 0; ks < 2; ++ks) {
      const int fo = fofs0 ^ (ks << 6);
      bf16x8 a0 = *(const bf16x8*)(smem + arow * 128 + fo);
      bf16x8 a1 = *(const bf16x8*)(smem + (arow + 16) * 128 + fo);
      #pragma unroll
      for (int fn = 0; fn < 8; ++fn) {
        bf16x8 bb = *(const bf16x8*)(smem + 16384 + (brow + fn * 16) * 128 + fo);
        acc[0][fn] = __builtin_amdgcn_mfma_f32_16x16x32_bf16(a0, bb, acc[0][fn], 0, 0, 0);
        acc[1][fn] = __builtin_amdgcn_mfma_f32_16x16x32_bf16(a1, bb, acc[1][fn], 0, 0, 0);
      }
    }
  }
  #pragma unroll
  for (int fn = 0; fn < 8; ++fn) {
    int ncol = n0 + fn * 16 + (lane & 15);
    float bv = bias[ncol];
    #pragma unroll
    for (int mf = 0; mf < 2; ++mf) {
      int mrow = m0 + w * 32 + mf * 16 + ((lane >> 4) << 2);
      #pragma unroll
      for (int j = 0; j < 4; ++j) {
        float v = fmaxf(acc[mf][fn][j] + bv, 0.f);
        H[(size_t)(mrow + j) * 1024 + ncol] = __float2bfloat16(v);
      }
    }
  }
}

// ---------------------------------------------------------------------------
// GEMM2 + NCP: 256x256 tile over padded N=16384, BK=32, 4-deep LDS ring,
// counted vmcnt(8) (3-tile prefetch), 8 waves (2M x 4N), 2 phases/tile.
// LDS: 4 bufs x (A 16KB + B 16KB) = 128KB; epilogue reuses bytes 0..69759.
// ---------------------------------------------------------------------------
__global__ __launch_bounds__(512, 2) void gemm2_ncp_kernel(
    const __hip_bfloat16* __restrict__ Hin, const __hip_bfloat16* __restrict__ W2t,
    const float* __restrict__ b2, const float* __restrict__ zin,
    float* __restrict__ zout, float* __restrict__ logdet)
{
  __shared__ __align__(16) char smem[131072];
  const int tid = threadIdx.x;
  const int lane = tid & 63;
  const int w = tid >> 6;          // wave 0..7
  const int wr = w >> 2;           // 0..1  (M half)
  const int wc = w & 3;            // 0..3  (N quarter)
  const int m0 = blockIdx.x * 256;
  const int n0 = blockIdx.y * 256; // padded col base

  // staging: instr i covers 128 rows; wave w stages rows w*16..+15 of each half
  const char* gA = (const char*)Hin + (size_t)(m0 + w * 16 + (lane >> 2)) * 2048 + (lane & 3) * 16;
  const char* gB = (const char*)W2t + (size_t)(n0 + w * 16 + (lane >> 2)) * 2048 + (lane & 3) * 16;
  const int ldsw = w * 1024;       // wave-uniform LDS sub-base

  // fragment read offsets (linear row-major [256][64B]; contiguous 1KB per frag)
  const int abase = (wr * 128 + (lane & 15)) * 64 + (lane >> 4) * 16;
  const int bbase = (wc * 64  + (lane & 15)) * 64 + (lane >> 4) * 16 + 16384;

  auto stageA = [&](int ts) {
    char* q = smem + ((ts & 3) << 15);
    gload_lds16(gA + ts * 64,          q + ldsw);
    gload_lds16(gA + 262144 + ts * 64, q + 8192 + ldsw);
  };
  auto stageB = [&](int ts) {
    char* q = smem + ((ts & 3) << 15);
    gload_lds16(gB + ts * 64,          q + 16384 + ldsw);
    gload_lds16(gB + 262144 + ts * 64, q + 24576 + ldsw);
  };

  f32x4 acc[8][4];
  #pragma unroll
  for (int i = 0; i < 8; ++i)
    #pragma unroll
    for (int j = 0; j < 4; ++j) acc[i][j] = (f32x4){0.f, 0.f, 0.f, 0.f};

  // prologue: prefetch tiles 0,1,2 (12 loads)
  stageA(0); stageB(0); stageA(1); stageB(1); stageA(2); stageB(2);

  for (int t = 0; t < 32; ++t) {
    // own S(t) loads are older than the 8 newest (S(t+1),S(t+2)) -> forced done
    asm volatile("s_waitcnt vmcnt(8)" ::: "memory");
    __builtin_amdgcn_s_barrier();   // all waves' S(t) landed; prev-tile reads done

    const char* LA = smem + ((t & 3) << 15);
    int ts = t + 3; if (ts > 31) ts = 31;   // tail: idempotent dup re-stage of 31

    // ---- phase A: b-frags + a-frags 0..3, stage next A-halves, 16 MFMA ----
    bf16x8 bfr[4], afr[4];
    #pragma unroll
    for (int nf = 0; nf < 4; ++nf)
      bfr[nf] = *(const bf16x8*)(LA + bbase + nf * 1024);
    #pragma unroll
    for (int mf = 0; mf < 4; ++mf)
      afr[mf] = *(const bf16x8*)(LA + abase + mf * 1024);
    if (t < 31) stageA(ts);
    __builtin_amdgcn_s_setprio(1);
    #pragma unroll
    for (int mf = 0; mf < 4; ++mf)
      #pragma unroll
      for (int nf = 0; nf < 4; ++nf)
        acc[mf][nf] = __builtin_amdgcn_mfma_f32_16x16x32_bf16(afr[mf], bfr[nf], acc[mf][nf], 0, 0, 0);
    __builtin_amdgcn_s_setprio(0);

    // ---- phase B: a-frags 4..7, stage next B-halves, 16 MFMA ----
    bf16x8 afr2[4];
    #pragma unroll
    for (int mf = 0; mf < 4; ++mf)
      afr2[mf] = *(const bf16x8*)(LA + abase + (mf + 4) * 1024);
    if (t < 31) stageB(ts);
    __builtin_amdgcn_s_setprio(1);
    #pragma unroll
    for (int mf = 0; mf < 4; ++mf)
      #pragma unroll
      for (int nf = 0; nf < 4; ++nf)
        acc[mf + 4][nf] = __builtin_amdgcn_mfma_f32_16x16x32_bf16(afr2[mf], bfr[nf], acc[mf + 4][nf], 0, 0, 0);
    __builtin_amdgcn_s_setprio(0);
  }

  asm volatile("s_waitcnt vmcnt(0)" ::: "memory");
  __builtin_amdgcn_s_barrier();

  // ---- fused NCP epilogue: 4 chunk-pairs of 64 rows ----
  float* ep  = (float*)smem;                   // [64][264] f32 (XOR-swizzled cols)
  float* ldp = (float*)(smem + 67584);         // [8][68] f32 partial log-dets

  float b2v[4];
  #pragma unroll
  for (int nf = 0; nf < 4; ++nf) {
    int cglob = n0 + wc * 64 + nf * 16 + (lane & 15);
    int tg = cglob >> 5, jj = cglob & 31;
    b2v[nf] = (jj < 30) ? b2[tg * 30 + jj] : 0.f;
  }

  const int r = lane;                          // local row 0..63 (reader role)
  const int g = w;                             // t-group 0..7  (reader role)
  const int tglob = blockIdx.y * 8 + g;

  for (int pair = 0; pair < 4; ++pair) {
    __syncthreads();
    if (wr == (pair >> 1)) {                   // owning waves write 64 rows
      const int mb = (pair & 1) * 4;
      #pragma unroll
      for (int mfl = 0; mfl < 4; ++mfl) {
        #pragma unroll
        for (int j = 0; j < 4; ++j) {
          const int row = mfl * 16 + ((lane >> 4) << 2) + j;
          const int rk = ((row >> 2) & 7) << 3;
          float* eprow = ep + row * 264;
          #pragma unroll
          for (int nf = 0; nf < 4; ++nf) {
            const int col = wc * 64 + nf * 16 + (lane & 15);
            eprow[col ^ rk] = acc[mb + mfl][nf][j] + b2v[nf];
          }
        }
      }
    }
    __syncthreads();

    // one thread per (row, t-group)
    float o[32];
    const int key = ((r >> 2) & 7) << 3;
    #pragma unroll
    for (int k = 0; k < 8; ++k) {
      f32x4 v = *(const f32x4*)(ep + r * 264 + ((g * 32 + 4 * k) ^ key));
      o[4 * k + 0] = v[0]; o[4 * k + 1] = v[1];
      o[4 * k + 2] = v[2]; o[4 * k + 3] = v[3];
    }

    const int bidx = m0 + pair * 64 + r;
    const float phi = zin[(size_t)bidx * 1024 + 2 * tglob + 1];
    const float x = tanf(0.5f * (phi - PI_F));
    const float x2p1 = fmaf(x, x, 1.0f);

    float mx = -1e30f;
    #pragma unroll
    for (int e = 0; e < 10; ++e) mx = fmaxf(mx, o[3 * e + 2]);

    float s = 0.f, outv = 0.f, dsum = 0.f;
    #pragma unroll
    for (int e = 0; e < 10; ++e) {
      float re = __expf(o[3 * e + 2] - mx);
      s += re;
      float av = o[3 * e];
      float aa = fmaxf(av, 0.f) + __logf(1.f + __expf(-fabsf(av))) + 0.001f;
      float u = fmaf(aa, x, o[3 * e + 1]);
      outv = fmaf(re, fmaf(2.f, atanf(u), PI_F), outv);
      dsum = fmaf(re, aa * x2p1 / fmaf(u, u, 1.f), dsum);
    }
    float inv = 1.f / s;
    zout[(size_t)bidx * 1024 + 2 * tglob + 1] = outv * inv;
    ldp[g * 68 + r] = __logf(dsum * inv);

    __syncthreads();
    if (tid < 64) {
      float sld = 0.f;
      #pragma unroll
      for (int gg = 0; gg < 8; ++gg) sld += ldp[gg * 68 + tid];
      atomicAdd(&logdet[m0 + pair * 64 + tid], sld);
    }
  }
}

// ---------------------------------------------------------------------------
extern "C" void kernel_launch(void* const* d_in, const int* in_sizes, int n_in,
                              void* d_out, int out_size, void* d_ws, size_t ws_size,
                              hipStream_t stream) {
  const float* z  = (const float*)d_in[0];
  const float* W1 = (const float*)d_in[1];
  const float* b1 = (const float*)d_in[2];
  const float* W2 = (const float*)d_in[3];
  const float* b2 = (const float*)d_in[4];

  float* zout   = (float*)d_out;               // 8192*1024
  float* logdet = zout + (size_t)8192 * 1024;  // 8192

  // ws layout (64 MiB total): hB 0..16M, W1T 16..18M, featB 32..48M (dead
  // after gemm1), W2Tp 32..64M (written after gemm1, overlays featB).
  char* ws = (char*)d_ws;
  __hip_bfloat16* hB    = (__hip_bfloat16*)ws;
  __hip_bfloat16* W1T   = (__hip_bfloat16*)(ws + 16777216);
  __hip_bfloat16* featB = (__hip_bfloat16*)(ws + 33554432);
  __hip_bfloat16* W2Tp  = (__hip_bfloat16*)(ws + 33554432);

  prep_feat_kernel<<<16384, 256, 0, stream>>>(z, featB, zout, logdet);
  transpose_bf16_kernel<<<dim3(32, 32), dim3(32, 8), 0, stream>>>(W1, W1T, 1024, 1024);
  gemm1_kernel<<<dim3(64, 8), 256, 0, stream>>>(featB, W1T, b1, hB);
  transpose_w2_pad_kernel<<<dim3(512, 32), dim3(32, 8), 0, stream>>>(W2, W2Tp);
  gemm2_ncp_kernel<<<dim3(32, 64), 512, 0, stream>>>(hB, W2Tp, b2, z, zout, logdet);
}

// Round 3
// 503.412 us; speedup vs baseline: 1.5343x; 1.5343x over previous
//
#include <hip/hip_runtime.h>
#include <hip/hip_bf16.h>
#include <cstdint>

#define PI_F 3.14159265358979323846f

typedef __attribute__((ext_vector_type(8))) short bf16x8;
typedef __attribute__((ext_vector_type(4))) float f32x4;

__device__ __forceinline__ void gload_lds16(const void* g, void* l) {
  __builtin_amdgcn_global_load_lds(
      (const __attribute__((address_space(1))) void*)g,
      (__attribute__((address_space(3))) void*)l, 16, 0, 0);
}

// ---------------------------------------------------------------------------
// prep: feat = [cos(cond), sin(cond)] as bf16; z_new even cols = cond; zero ld
// ---------------------------------------------------------------------------
__global__ __launch_bounds__(256) void prep_feat_kernel(
    const float* __restrict__ z, __hip_bfloat16* __restrict__ feat,
    float* __restrict__ zout, float* __restrict__ logdet)
{
  int idx = blockIdx.x * 256 + threadIdx.x;    // B*512 threads
  int b = idx >> 9, j = idx & 511;
  float2 zz = ((const float2*)z)[idx];         // z[b][2j], z[b][2j+1]
  feat[(size_t)b * 1024 + j]       = __float2bfloat16(cosf(zz.x));
  feat[(size_t)b * 1024 + 512 + j] = __float2bfloat16(sinf(zz.x));
  zout[(size_t)b * 1024 + 2 * j]   = zz.x;
  if (idx < 8192) logdet[idx] = 0.f;
}

// ---------------------------------------------------------------------------
// transpose f32 [R][C] -> bf16 [C][R]   (used for W1)
// ---------------------------------------------------------------------------
__global__ __launch_bounds__(256) void transpose_bf16_kernel(
    const float* __restrict__ src, __hip_bfloat16* __restrict__ dst, int R, int C)
{
  __shared__ float tile[32][33];
  int c0 = blockIdx.x * 32, r0 = blockIdx.y * 32;
  int x = threadIdx.x, y = threadIdx.y;        // 32 x 8
  #pragma unroll
  for (int i = 0; i < 32; i += 8)
    tile[y + i][x] = src[(size_t)(r0 + y + i) * C + c0 + x];
  __syncthreads();
  #pragma unroll
  for (int i = 0; i < 32; i += 8)
    dst[(size_t)(c0 + y + i) * R + r0 + x] = __float2bfloat16(tile[x][y + i]);
}

// ---------------------------------------------------------------------------
// W2 transpose with t-group padding: out[t*32+j][k] = W2[k][t*30+j] (j<30), 0 pad
// out is [16384][1024] bf16.
// ---------------------------------------------------------------------------
__global__ __launch_bounds__(256) void transpose_w2_pad_kernel(
    const float* __restrict__ W2, __hip_bfloat16* __restrict__ dst)
{
  __shared__ float tile[32][33];
  int t = blockIdx.x;                          // 0..511
  int k0 = blockIdx.y * 32;                    // 0..991
  int x = threadIdx.x, y = threadIdx.y;        // 32 x 8
  #pragma unroll
  for (int i = 0; i < 32; i += 8)
    tile[y + i][x] = (x < 30) ? W2[(size_t)(k0 + y + i) * 15360 + t * 30 + x] : 0.f;
  __syncthreads();
  #pragma unroll
  for (int i = 0; i < 32; i += 8)
    dst[(size_t)(t * 32 + y + i) * 1024 + k0 + x] = __float2bfloat16(tile[x][y + i]);
}

// ---------------------------------------------------------------------------
// GEMM1: h = relu(feat @ W1 + b1), M=8192 N=1024 K=1024, out bf16 (unchanged)
// ---------------------------------------------------------------------------
__global__ __launch_bounds__(256, 2) void gemm1_kernel(
    const __hip_bfloat16* __restrict__ A, const __hip_bfloat16* __restrict__ Bt,
    const float* __restrict__ bias, __hip_bfloat16* __restrict__ H)
{
  __shared__ __align__(16) char smem[32768];
  const int tid = threadIdx.x;
  const int lane = tid & 63;
  const int w = tid >> 6;
  const int m0 = blockIdx.x * 128;
  const int n0 = blockIdx.y * 128;
  const int lrow = lane >> 3;
  const int scol = ((lane & 7) ^ lrow) << 4;
  const int fofs0 = ((lane >> 4) << 4) ^ ((lane & 7) << 4);
  const int arow = w * 32 + (lane & 15);
  const int brow = (lane & 15);

  f32x4 acc[2][8];
  #pragma unroll
  for (int i = 0; i < 2; ++i)
    #pragma unroll
    for (int j = 0; j < 8; ++j) acc[i][j] = (f32x4){0.f, 0.f, 0.f, 0.f};

  const char* Abase = (const char*)A + (size_t)(m0 + lrow) * 2048 + scol;
  const char* Bbase = (const char*)Bt + (size_t)(n0 + lrow) * 2048 + scol;

  for (int kt = 0; kt < 16; ++kt) {
    const int k0b = kt * 128;
    __syncthreads();
    #pragma unroll
    for (int i = 0; i < 8; ++i) {
      int c = w + i * 4;
      if (c < 16) gload_lds16(Abase + (size_t)c * 16384 + k0b, smem + c * 1024);
      else        gload_lds16(Bbase + (size_t)(c - 16) * 16384 + k0b,
                              smem + 16384 + (c - 16) * 1024);
    }
    asm volatile("s_waitcnt vmcnt(0)" ::: "memory");
    __syncthreads();
    #pragma unroll
    for (int ks = 0; ks < 2; ++ks) {
      const int fo = fofs0 ^ (ks << 6);
      bf16x8 a0 = *(const bf16x8*)(smem + arow * 128 + fo);
      bf16x8 a1 = *(const bf16x8*)(smem + (arow + 16) * 128 + fo);
      #pragma unroll
      for (int fn = 0; fn < 8; ++fn) {
        bf16x8 bb = *(const bf16x8*)(smem + 16384 + (brow + fn * 16) * 128 + fo);
        acc[0][fn] = __builtin_amdgcn_mfma_f32_16x16x32_bf16(a0, bb, acc[0][fn], 0, 0, 0);
        acc[1][fn] = __builtin_amdgcn_mfma_f32_16x16x32_bf16(a1, bb, acc[1][fn], 0, 0, 0);
      }
    }
  }
  #pragma unroll
  for (int fn = 0; fn < 8; ++fn) {
    int ncol = n0 + fn * 16 + (lane & 15);
    float bv = bias[ncol];
    #pragma unroll
    for (int mf = 0; mf < 2; ++mf) {
      int mrow = m0 + w * 32 + mf * 16 + ((lane >> 4) << 2);
      #pragma unroll
      for (int j = 0; j < 4; ++j) {
        float v = fmaxf(acc[mf][fn][j] + bv, 0.f);
        H[(size_t)(mrow + j) * 1024 + ncol] = __float2bfloat16(v);
      }
    }
  }
}

// ---------------------------------------------------------------------------
// GEMM2 + NCP: 256x256 tile over padded N=16384, BK=32, 4-deep LDS ring,
// counted vmcnt(8) (3-tile prefetch), 8 waves (2M x 4N), 2 phases/tile.
// LDS[r][c] = G[r][c ^ ((r>>2)&3)] via pre-swizzled global source (dest linear)
// -> fragment ds_read_b128 is bank-balanced (2 lanes/slot). acc fully static.
// ---------------------------------------------------------------------------
__global__ __launch_bounds__(512, 2) void gemm2_ncp_kernel(
    const __hip_bfloat16* __restrict__ Hin, const __hip_bfloat16* __restrict__ W2t,
    const float* __restrict__ b2, const float* __restrict__ zin,
    float* __restrict__ zout, float* __restrict__ logdet)
{
  __shared__ __align__(16) char smem[131072];  // 4 bufs x (A 16KB + B 16KB)
  const int tid = threadIdx.x;
  const int lane = tid & 63;
  const int w = tid >> 6;          // wave 0..7
  const int wr = w >> 2;           // 0..1  (M half)
  const int wc = w & 3;            // 0..3  (N quarter)

  // bijective XCD-aware swizzle of the 32x64 grid (nwg=2048, %8==0)
  const int lin = blockIdx.y * 32 + blockIdx.x;
  const int swz = (lin & 7) * 256 + (lin >> 3);
  const int bx = swz & 31, by = swz >> 5;
  const int m0 = bx * 256;
  const int n0 = by * 256;         // padded col base

  // staging: per matrix 2 instrs/wave; wave w covers rows w*16..+15 (+128).
  // source chunk pre-swizzled: chunk = (lane&3) ^ (lane>>4)  [dest linear]
  const char* gA = (const char*)Hin +
      (size_t)(m0 + w * 16 + (lane >> 2)) * 2048 + (((lane & 3) ^ (lane >> 4)) << 4);
  const char* gB = (const char*)W2t +
      (size_t)(n0 + w * 16 + (lane >> 2)) * 2048 + (((lane & 3) ^ (lane >> 4)) << 4);
  const int ldsw = w * 1024;       // wave-uniform LDS sub-base

  // fragment read offsets: row r, need chunk q=lane>>4 stored at q^((r>>2)&3)
  const int csw = ((lane >> 4) ^ ((lane >> 2) & 3)) << 4;
  const int abase = (wr * 128 + (lane & 15)) * 64 + csw;
  const int bbase = (wc * 64  + (lane & 15)) * 64 + csw + 16384;

  auto stageA = [&](int ts) {
    char* q = smem + ((ts & 3) << 15);
    gload_lds16(gA + ts * 64,          q + ldsw);
    gload_lds16(gA + 262144 + ts * 64, q + 8192 + ldsw);
  };
  auto stageB = [&](int ts) {
    char* q = smem + ((ts & 3) << 15);
    gload_lds16(gB + ts * 64,          q + 16384 + ldsw);
    gload_lds16(gB + 262144 + ts * 64, q + 24576 + ldsw);
  };

  f32x4 acc[8][4];
  #pragma unroll
  for (int i = 0; i < 8; ++i)
    #pragma unroll
    for (int j = 0; j < 4; ++j) acc[i][j] = (f32x4){0.f, 0.f, 0.f, 0.f};

  // prologue: prefetch tiles 0,1,2 (12 loads/wave)
  stageA(0); stageB(0); stageA(1); stageB(1); stageA(2); stageB(2);

  for (int t = 0; t < 32; ++t) {
    // own S(t) loads are older than the 8 newest (S(t+1),S(t+2)) -> forced done
    asm volatile("s_waitcnt vmcnt(8)" ::: "memory");
    __builtin_amdgcn_s_barrier();   // all waves' S(t) landed; prev reads done

    const char* LA = smem + ((t & 3) << 15);
    int ts = t + 3; if (ts > 31) ts = 31;   // tail: idempotent dup re-stage

    // ---- phase A: b-frags + a-frags 0..3, stage next A, 16 MFMA ----
    bf16x8 bfr[4], afr[4];
    #pragma unroll
    for (int nf = 0; nf < 4; ++nf)
      bfr[nf] = *(const bf16x8*)(LA + bbase + nf * 1024);
    #pragma unroll
    for (int mf = 0; mf < 4; ++mf)
      afr[mf] = *(const bf16x8*)(LA + abase + mf * 1024);
    if (t < 31) stageA(ts);
    __builtin_amdgcn_s_setprio(1);
    #pragma unroll
    for (int mf = 0; mf < 4; ++mf)
      #pragma unroll
      for (int nf = 0; nf < 4; ++nf)
        acc[mf][nf] = __builtin_amdgcn_mfma_f32_16x16x32_bf16(afr[mf], bfr[nf], acc[mf][nf], 0, 0, 0);
    __builtin_amdgcn_s_setprio(0);

    // ---- phase B: a-frags 4..7, stage next B, 16 MFMA ----
    bf16x8 afr2[4];
    #pragma unroll
    for (int mf = 0; mf < 4; ++mf)
      afr2[mf] = *(const bf16x8*)(LA + abase + (mf + 4) * 1024);
    if (t < 31) stageB(ts);
    __builtin_amdgcn_s_setprio(1);
    #pragma unroll
    for (int mf = 0; mf < 4; ++mf)
      #pragma unroll
      for (int nf = 0; nf < 4; ++nf)
        acc[mf + 4][nf] = __builtin_amdgcn_mfma_f32_16x16x32_bf16(afr2[mf], bfr[nf], acc[mf + 4][nf], 0, 0, 0);
    __builtin_amdgcn_s_setprio(0);
  }

  asm volatile("s_waitcnt vmcnt(0)" ::: "memory");
  __builtin_amdgcn_s_barrier();

  // ---- fused NCP epilogue: 4 chunk-pairs of 64 rows (fully unrolled) ----
  float* ep  = (float*)smem;                   // [64][264] f32 (XOR-swizzled)
  float* ldp = (float*)(smem + 67584);         // [8][68] f32 partial log-dets

  float b2v[4];
  #pragma unroll
  for (int nf = 0; nf < 4; ++nf) {
    int cglob = n0 + wc * 64 + nf * 16 + (lane & 15);
    int tg = cglob >> 5, jj = cglob & 31;
    b2v[nf] = (jj < 30) ? b2[tg * 30 + jj] : 0.f;
  }

  const int r = lane;                          // local row 0..63 (reader role)
  const int g = w;                             // t-group 0..7  (reader role)
  const int tglob = by * 8 + g;

  #pragma unroll
  for (int pair = 0; pair < 4; ++pair) {
    __syncthreads();
    if (wr == (pair >> 1)) {                   // owning waves write 64 rows
      const int mb = (pair & 1) * 4;           // compile-time after unroll
      #pragma unroll
      for (int mfl = 0; mfl < 4; ++mfl) {
        #pragma unroll
        for (int j = 0; j < 4; ++j) {
          const int row = mfl * 16 + ((lane >> 4) << 2) + j;
          const int rk = ((row >> 2) & 7) << 3;
          float* eprow = ep + row * 264;
          #pragma unroll
          for (int nf = 0; nf < 4; ++nf) {
            const int col = wc * 64 + nf * 16 + (lane & 15);
            eprow[col ^ rk] = acc[mb + mfl][nf][j] + b2v[nf];
          }
        }
      }
    }
    __syncthreads();

    // one thread per (row, t-group)
    float o[32];
    const int key = ((r >> 2) & 7) << 3;
    #pragma unroll
    for (int k = 0; k < 8; ++k) {
      f32x4 v = *(const f32x4*)(ep + r * 264 + ((g * 32 + 4 * k) ^ key));
      o[4 * k + 0] = v[0]; o[4 * k + 1] = v[1];
      o[4 * k + 2] = v[2]; o[4 * k + 3] = v[3];
    }

    const int bidx = m0 + pair * 64 + r;
    const float phi = zin[(size_t)bidx * 1024 + 2 * tglob + 1];
    const float x = tanf(0.5f * (phi - PI_F));
    const float x2p1 = fmaf(x, x, 1.0f);

    float mx = -1e30f;
    #pragma unroll
    for (int e = 0; e < 10; ++e) mx = fmaxf(mx, o[3 * e + 2]);

    float s = 0.f, outv = 0.f, dsum = 0.f;
    #pragma unroll
    for (int e = 0; e < 10; ++e) {
      float re = __expf(o[3 * e + 2] - mx);
      s += re;
      float av = o[3 * e];
      float aa = fmaxf(av, 0.f) + __logf(1.f + __expf(-fabsf(av))) + 0.001f;
      float u = fmaf(aa, x, o[3 * e + 1]);
      outv = fmaf(re, fmaf(2.f, atanf(u), PI_F), outv);
      dsum = fmaf(re, aa * x2p1 / fmaf(u, u, 1.f), dsum);
    }
    float inv = 1.f / s;
    zout[(size_t)bidx * 1024 + 2 * tglob + 1] = outv * inv;
    ldp[g * 68 + r] = __logf(dsum * inv);

    __syncthreads();
    if (tid < 64) {
      float sld = 0.f;
      #pragma unroll
      for (int gg = 0; gg < 8; ++gg) sld += ldp[gg * 68 + tid];
      atomicAdd(&logdet[m0 + pair * 64 + tid], sld);
    }
  }
}

// ---------------------------------------------------------------------------
extern "C" void kernel_launch(void* const* d_in, const int* in_sizes, int n_in,
                              void* d_out, int out_size, void* d_ws, size_t ws_size,
                              hipStream_t stream) {
  const float* z  = (const float*)d_in[0];
  const float* W1 = (const float*)d_in[1];
  const float* b1 = (const float*)d_in[2];
  const float* W2 = (const float*)d_in[3];
  const float* b2 = (const float*)d_in[4];

  float* zout   = (float*)d_out;               // 8192*1024
  float* logdet = zout + (size_t)8192 * 1024;  // 8192

  // ws layout (64 MiB): hB 0..16M, W1T 16..18M, featB 32..48M (dead after
  // gemm1), W2Tp 32..64M (written after gemm1, overlays featB).
  char* ws = (char*)d_ws;
  __hip_bfloat16* hB    = (__hip_bfloat16*)ws;
  __hip_bfloat16* W1T   = (__hip_bfloat16*)(ws + 16777216);
  __hip_bfloat16* featB = (__hip_bfloat16*)(ws + 33554432);
  __hip_bfloat16* W2Tp  = (__hip_bfloat16*)(ws + 33554432);

  prep_feat_kernel<<<16384, 256, 0, stream>>>(z, featB, zout, logdet);
  transpose_bf16_kernel<<<dim3(32, 32), dim3(32, 8), 0, stream>>>(W1, W1T, 1024, 1024);
  gemm1_kernel<<<dim3(64, 8), 256, 0, stream>>>(featB, W1T, b1, hB);
  transpose_w2_pad_kernel<<<dim3(512, 32), dim3(32, 8), 0, stream>>>(W2, W2Tp);
  gemm2_ncp_kernel<<<dim3(32, 64), 512, 0, stream>>>(hB, W2Tp, b2, z, zout, logdet);
}

// Round 4
// 489.756 us; speedup vs baseline: 1.5771x; 1.0279x over previous
//
#include <hip/hip_runtime.h>
#include <hip/hip_bf16.h>
#include <cstdint>

#define PI_F 3.14159265358979323846f

typedef __attribute__((ext_vector_type(8))) short bf16x8;
typedef __attribute__((ext_vector_type(4))) float f32x4;

#define BARRIER()  asm volatile("s_barrier" ::: "memory")
#define LGKM0()    asm volatile("s_waitcnt lgkmcnt(0)" ::: "memory")

__device__ __forceinline__ void gload_lds16(const void* g, void* l) {
  __builtin_amdgcn_global_load_lds(
      (const __attribute__((address_space(1))) void*)g,
      (__attribute__((address_space(3))) void*)l, 16, 0, 0);
}

// ---------------------------------------------------------------------------
// prep: feat = [cos(cond), sin(cond)] as bf16; z_new even cols = cond; zero ld
// ---------------------------------------------------------------------------
__global__ __launch_bounds__(256) void prep_feat_kernel(
    const float* __restrict__ z, __hip_bfloat16* __restrict__ feat,
    float* __restrict__ zout, float* __restrict__ logdet)
{
  int idx = blockIdx.x * 256 + threadIdx.x;    // B*512 threads
  int b = idx >> 9, j = idx & 511;
  float2 zz = ((const float2*)z)[idx];         // z[b][2j], z[b][2j+1]
  feat[(size_t)b * 1024 + j]       = __float2bfloat16(cosf(zz.x));
  feat[(size_t)b * 1024 + 512 + j] = __float2bfloat16(sinf(zz.x));
  zout[(size_t)b * 1024 + 2 * j]   = zz.x;
  if (idx < 8192) logdet[idx] = 0.f;
}

// ---------------------------------------------------------------------------
// transpose f32 [R][C] -> bf16 [C][R]   (used for W1)
// ---------------------------------------------------------------------------
__global__ __launch_bounds__(256) void transpose_bf16_kernel(
    const float* __restrict__ src, __hip_bfloat16* __restrict__ dst, int R, int C)
{
  __shared__ float tile[32][33];
  int c0 = blockIdx.x * 32, r0 = blockIdx.y * 32;
  int x = threadIdx.x, y = threadIdx.y;        // 32 x 8
  #pragma unroll
  for (int i = 0; i < 32; i += 8)
    tile[y + i][x] = src[(size_t)(r0 + y + i) * C + c0 + x];
  __syncthreads();
  #pragma unroll
  for (int i = 0; i < 32; i += 8)
    dst[(size_t)(c0 + y + i) * R + r0 + x] = __float2bfloat16(tile[x][y + i]);
}

// ---------------------------------------------------------------------------
// W2 transpose with t-group padding: out[t*32+j][k] = W2[k][t*30+j] (j<30), 0 pad
// ---------------------------------------------------------------------------
__global__ __launch_bounds__(256) void transpose_w2_pad_kernel(
    const float* __restrict__ W2, __hip_bfloat16* __restrict__ dst)
{
  __shared__ float tile[32][33];
  int t = blockIdx.x;                          // 0..511
  int k0 = blockIdx.y * 32;                    // 0..991
  int x = threadIdx.x, y = threadIdx.y;        // 32 x 8
  #pragma unroll
  for (int i = 0; i < 32; i += 8)
    tile[y + i][x] = (x < 30) ? W2[(size_t)(k0 + y + i) * 15360 + t * 30 + x] : 0.f;
  __syncthreads();
  #pragma unroll
  for (int i = 0; i < 32; i += 8)
    dst[(size_t)(t * 32 + y + i) * 1024 + k0 + x] = __float2bfloat16(tile[x][y + i]);
}

// ---------------------------------------------------------------------------
// GEMM1: h = relu(feat @ W1 + b1), M=8192 N=1024 K=1024, out bf16 (unchanged)
// ---------------------------------------------------------------------------
__global__ __launch_bounds__(256, 2) void gemm1_kernel(
    const __hip_bfloat16* __restrict__ A, const __hip_bfloat16* __restrict__ Bt,
    const float* __restrict__ bias, __hip_bfloat16* __restrict__ H)
{
  __shared__ __align__(16) char smem[32768];
  const int tid = threadIdx.x;
  const int lane = tid & 63;
  const int w = tid >> 6;
  const int m0 = blockIdx.x * 128;
  const int n0 = blockIdx.y * 128;
  const int lrow = lane >> 3;
  const int scol = ((lane & 7) ^ lrow) << 4;
  const int fofs0 = ((lane >> 4) << 4) ^ ((lane & 7) << 4);
  const int arow = w * 32 + (lane & 15);
  const int brow = (lane & 15);

  f32x4 acc[2][8];
  #pragma unroll
  for (int i = 0; i < 2; ++i)
    #pragma unroll
    for (int j = 0; j < 8; ++j) acc[i][j] = (f32x4){0.f, 0.f, 0.f, 0.f};

  const char* Abase = (const char*)A + (size_t)(m0 + lrow) * 2048 + scol;
  const char* Bbase = (const char*)Bt + (size_t)(n0 + lrow) * 2048 + scol;

  for (int kt = 0; kt < 16; ++kt) {
    const int k0b = kt * 128;
    __syncthreads();
    #pragma unroll
    for (int i = 0; i < 8; ++i) {
      int c = w + i * 4;
      if (c < 16) gload_lds16(Abase + (size_t)c * 16384 + k0b, smem + c * 1024);
      else        gload_lds16(Bbase + (size_t)(c - 16) * 16384 + k0b,
                              smem + 16384 + (c - 16) * 1024);
    }
    asm volatile("s_waitcnt vmcnt(0)" ::: "memory");
    __syncthreads();
    #pragma unroll
    for (int ks = 0; ks < 2; ++ks) {
      const int fo = fofs0 ^ (ks << 6);
      bf16x8 a0 = *(const bf16x8*)(smem + arow * 128 + fo);
      bf16x8 a1 = *(const bf16x8*)(smem + (arow + 16) * 128 + fo);
      #pragma unroll
      for (int fn = 0; fn < 8; ++fn) {
        bf16x8 bb = *(const bf16x8*)(smem + 16384 + (brow + fn * 16) * 128 + fo);
        acc[0][fn] = __builtin_amdgcn_mfma_f32_16x16x32_bf16(a0, bb, acc[0][fn], 0, 0, 0);
        acc[1][fn] = __builtin_amdgcn_mfma_f32_16x16x32_bf16(a1, bb, acc[1][fn], 0, 0, 0);
      }
    }
  }
  #pragma unroll
  for (int fn = 0; fn < 8; ++fn) {
    int ncol = n0 + fn * 16 + (lane & 15);
    float bv = bias[ncol];
    #pragma unroll
    for (int mf = 0; mf < 2; ++mf) {
      int mrow = m0 + w * 32 + mf * 16 + ((lane >> 4) << 2);
      #pragma unroll
      for (int j = 0; j < 4; ++j) {
        float v = fmaxf(acc[mf][fn][j] + bv, 0.f);
        H[(size_t)(mrow + j) * 1024 + ncol] = __float2bfloat16(v);
      }
    }
  }
}

// ---------------------------------------------------------------------------
// GEMM2 + NCP, 8-phase schedule (m201 port): 256x256 tile, BK=64, 2 LDS bufs
// (even/odd K-tile), 8 waves (2M x 4N). Per iter = 2 K-tiles = 8 phases of
// {ds_read subtile | stage | barrier | 16 MFMA | lgkm-drain | barrier}.
// Counted vmcnt(8) at phases 3/7 only. Fragment reads XOR-swizzled
// (slot = chunk ^ (row&7)) via pre-swizzled global source, linear DMA dest.
// ---------------------------------------------------------------------------
__global__ __launch_bounds__(512, 2) void gemm2_ncp_kernel(
    const __hip_bfloat16* __restrict__ Hin, const __hip_bfloat16* __restrict__ W2t,
    const float* __restrict__ b2, const float* __restrict__ zin,
    float* __restrict__ zout, float* __restrict__ logdet)
{
  __shared__ __align__(16) char smem[131072];
  const int tid = threadIdx.x;
  const int lane = tid & 63;
  const int w = tid >> 6;          // wave 0..7
  const int wr = w >> 2;           // 0..1  (M half)
  const int wc = w & 3;            // 0..3  (N quarter)

  // XCD swizzle: physical p -> XCD p%8 owns 4 consecutive A-panels (bx), all by
  const int p = blockIdx.y * 32 + blockIdx.x;  // 0..2047
  const int lin = (p & 7) * 256 + (p >> 3);
  const int bx = lin >> 6, by = lin & 63;
  const int m0 = bx * 256, n0 = by * 256;

  // ---- staging (global -> LDS, linear dest, pre-swizzled source chunk) ----
  // one gload/wave = 1KB slice of an 8KB 64-row G::load; row = 8w + lane>>3
  const int srow = 8 * w + (lane >> 3);
  const int sswz = (((lane >> 3) ^ lane) & 7) << 4;   // chunk ^ (row&7)
  const char* gA = (const char*)Hin + (size_t)(m0 + srow) * 2048 + sswz;
  const char* gB = (const char*)W2t + (size_t)(n0 + srow) * 2048 + sswz;

  char* const A0 = smem;            // buffer0 (even K-tiles) A: 256x128B
  char* const B0 = smem + 32768;
  char* const A1 = smem + 65536;    // buffer1 (odd K-tiles)
  char* const B1 = smem + 98304;
  const int ldst = w * 1024;        // wave-uniform; +lane*16 by HW

  auto stA = [&](char* buf, int kt, int L) {
    gload_lds16(gA + (size_t)L * 131072 + kt * 128, buf + L * 8192 + ldst);
  };
  auto stB = [&](char* buf, int kt, int L) {
    gload_lds16(gB + (size_t)L * 131072 + kt * 128, buf + L * 8192 + ldst);
  };

  // ---- fragment read offsets: row r reads chunk q at slot q^(r&7) ----
  const int aoff = (lane & 15) * 128 + ((((lane >> 4) ^ lane) & 7) << 4);
  const int arb = wr * 16384 + aoff;   // kk=1: ^64
  const int brb = wc * 8192 + aoff;

  f32x4 acc[8][4];
  #pragma unroll
  for (int i = 0; i < 8; ++i)
    #pragma unroll
    for (int j = 0; j < 4; ++j) acc[i][j] = (f32x4){0.f, 0.f, 0.f, 0.f};

  bf16x8 a0f[4][2], a1f[4][2], bfr[4];

  // ---- prologue: stage K0 -> buf0, K1 -> buf1; force K0 complete ----
  #pragma unroll
  for (int L = 0; L < 4; ++L) stA(A0, 0, L);
  #pragma unroll
  for (int L = 0; L < 4; ++L) stB(B0, 0, L);
  #pragma unroll
  for (int L = 0; L < 4; ++L) stA(A1, 1, L);
  #pragma unroll
  for (int L = 0; L < 4; ++L) stB(B1, 1, L);
  asm volatile("s_waitcnt vmcnt(8)" ::: "memory");
  BARRIER();

  for (int it = 0; it < 8; ++it) {
    const bool tail = (it == 7);
    const int ktA = 2 * it + 2, ktB = 2 * it + 3;

    // ---- p0: read A m0-3 (kk0+kk1) + B kk0 from buf0; MFMA m0-3 x kk0 ----
    #pragma unroll
    for (int m = 0; m < 4; ++m) {
      a0f[m][1] = *(const bf16x8*)(A0 + m * 2048 + (arb ^ 64));
      a0f[m][0] = *(const bf16x8*)(A0 + m * 2048 + arb);
    }
    #pragma unroll
    for (int n = 0; n < 4; ++n)
      bfr[n] = *(const bf16x8*)(B0 + n * 2048 + brb);
    BARRIER();
    __builtin_amdgcn_s_setprio(1);
    #pragma unroll
    for (int m = 0; m < 4; ++m)
      #pragma unroll
      for (int n = 0; n < 4; ++n)
        acc[m][n] = __builtin_amdgcn_mfma_f32_16x16x32_bf16(a0f[m][0], bfr[n], acc[m][n], 0, 0, 0);
    __builtin_amdgcn_s_setprio(0);
    LGKM0(); BARRIER();

    // ---- p1: read A m4-7 (kk1 first, then kk0); MFMA m4-7 x kk0 ----
    #pragma unroll
    for (int m = 0; m < 4; ++m) {
      a1f[m][1] = *(const bf16x8*)(A0 + (m + 4) * 2048 + (arb ^ 64));
      a1f[m][0] = *(const bf16x8*)(A0 + (m + 4) * 2048 + arb);
    }
    BARRIER();
    __builtin_amdgcn_s_setprio(1);
    #pragma unroll
    for (int m = 0; m < 4; ++m)
      #pragma unroll
      for (int n = 0; n < 4; ++n)
        acc[m + 4][n] = __builtin_amdgcn_mfma_f32_16x16x32_bf16(a1f[m][0], bfr[n], acc[m + 4][n], 0, 0, 0);
    __builtin_amdgcn_s_setprio(0);
    LGKM0(); BARRIER();

    // ---- p2: read B kk1; stage next-even A (buf0.A dead after p1); MFMA m0-3 kk1
    #pragma unroll
    for (int n = 0; n < 4; ++n)
      bfr[n] = *(const bf16x8*)(B0 + n * 2048 + (brb ^ 64));
    if (!tail) {
      #pragma unroll
      for (int L = 0; L < 4; ++L) stA(A0, ktA, L);
    }
    BARRIER();
    __builtin_amdgcn_s_setprio(1);
    #pragma unroll
    for (int m = 0; m < 4; ++m)
      #pragma unroll
      for (int n = 0; n < 4; ++n)
        acc[m][n] = __builtin_amdgcn_mfma_f32_16x16x32_bf16(a0f[m][1], bfr[n], acc[m][n], 0, 0, 0);
    __builtin_amdgcn_s_setprio(0);
    LGKM0(); BARRIER();

    // ---- p3: stage next-even B (buf0.B dead after p2); vmcnt forces buf1; MFMA m4-7 kk1
    if (!tail) {
      #pragma unroll
      for (int L = 0; L < 4; ++L) stB(B0, ktA, L);
      asm volatile("s_waitcnt vmcnt(8)" ::: "memory");
    } else {
      asm volatile("s_waitcnt vmcnt(0)" ::: "memory");
    }
    BARRIER();
    __builtin_amdgcn_s_setprio(1);
    #pragma unroll
    for (int m = 0; m < 4; ++m)
      #pragma unroll
      for (int n = 0; n < 4; ++n)
        acc[m + 4][n] = __builtin_amdgcn_mfma_f32_16x16x32_bf16(a1f[m][1], bfr[n], acc[m + 4][n], 0, 0, 0);
    __builtin_amdgcn_s_setprio(0);
    LGKM0(); BARRIER();

    // ---- p4: buf1 reads: A m0-3 + B kk0; MFMA m0-3 kk0 ----
    #pragma unroll
    for (int m = 0; m < 4; ++m) {
      a0f[m][1] = *(const bf16x8*)(A1 + m * 2048 + (arb ^ 64));
      a0f[m][0] = *(const bf16x8*)(A1 + m * 2048 + arb);
    }
    #pragma unroll
    for (int n = 0; n < 4; ++n)
      bfr[n] = *(const bf16x8*)(B1 + n * 2048 + brb);
    BARRIER();
    __builtin_amdgcn_s_setprio(1);
    #pragma unroll
    for (int m = 0; m < 4; ++m)
      #pragma unroll
      for (int n = 0; n < 4; ++n)
        acc[m][n] = __builtin_amdgcn_mfma_f32_16x16x32_bf16(a0f[m][0], bfr[n], acc[m][n], 0, 0, 0);
    __builtin_amdgcn_s_setprio(0);
    LGKM0(); BARRIER();

    // ---- p5: A m4-7; MFMA m4-7 kk0 ----
    #pragma unroll
    for (int m = 0; m < 4; ++m) {
      a1f[m][1] = *(const bf16x8*)(A1 + (m + 4) * 2048 + (arb ^ 64));
      a1f[m][0] = *(const bf16x8*)(A1 + (m + 4) * 2048 + arb);
    }
    BARRIER();
    __builtin_amdgcn_s_setprio(1);
    #pragma unroll
    for (int m = 0; m < 4; ++m)
      #pragma unroll
      for (int n = 0; n < 4; ++n)
        acc[m + 4][n] = __builtin_amdgcn_mfma_f32_16x16x32_bf16(a1f[m][0], bfr[n], acc[m + 4][n], 0, 0, 0);
    __builtin_amdgcn_s_setprio(0);
    LGKM0(); BARRIER();

    // ---- p6: B kk1; stage next-odd A; MFMA m0-3 kk1 ----
    #pragma unroll
    for (int n = 0; n < 4; ++n)
      bfr[n] = *(const bf16x8*)(B1 + n * 2048 + (brb ^ 64));
    if (!tail) {
      #pragma unroll
      for (int L = 0; L < 4; ++L) stA(A1, ktB, L);
    }
    BARRIER();
    __builtin_amdgcn_s_setprio(1);
    #pragma unroll
    for (int m = 0; m < 4; ++m)
      #pragma unroll
      for (int n = 0; n < 4; ++n)
        acc[m][n] = __builtin_amdgcn_mfma_f32_16x16x32_bf16(a0f[m][1], bfr[n], acc[m][n], 0, 0, 0);
    __builtin_amdgcn_s_setprio(0);
    LGKM0(); BARRIER();

    // ---- p7: stage next-odd B; vmcnt forces next-even; MFMA m4-7 kk1 ----
    if (!tail) {
      #pragma unroll
      for (int L = 0; L < 4; ++L) stB(B1, ktB, L);
      asm volatile("s_waitcnt vmcnt(8)" ::: "memory");
    }
    BARRIER();
    __builtin_amdgcn_s_setprio(1);
    #pragma unroll
    for (int m = 0; m < 4; ++m)
      #pragma unroll
      for (int n = 0; n < 4; ++n)
        acc[m + 4][n] = __builtin_amdgcn_mfma_f32_16x16x32_bf16(a1f[m][1], bfr[n], acc[m + 4][n], 0, 0, 0);
    __builtin_amdgcn_s_setprio(0);
    LGKM0(); BARRIER();
  }

  __syncthreads();

  // ---- fused NCP epilogue: 4 chunk-pairs of 64 rows; ep stride 260 (odd slot
  // stride -> all bank-quads; no XOR needed) ----
  float* ep  = (float*)smem;                   // [64][260] f32
  float* ldp = (float*)(smem + 66560);         // [8][68] f32

  float b2v[4];
  #pragma unroll
  for (int nf = 0; nf < 4; ++nf) {
    int cglob = n0 + wc * 64 + nf * 16 + (lane & 15);
    int tg = cglob >> 5, jj = cglob & 31;
    b2v[nf] = (jj < 30) ? b2[tg * 30 + jj] : 0.f;
  }

  const int r = lane;                          // local row 0..63 (reader role)
  const int g = w;                             // t-group 0..7  (reader role)
  const int tglob = by * 8 + g;

  #pragma unroll
  for (int pair = 0; pair < 4; ++pair) {
    __syncthreads();
    if (wr == (pair >> 1)) {                   // owning waves write 64 rows
      const int mb = (pair & 1) * 4;
      #pragma unroll
      for (int mfl = 0; mfl < 4; ++mfl) {
        #pragma unroll
        for (int j = 0; j < 4; ++j) {
          const int row = mfl * 16 + ((lane >> 4) << 2) + j;
          float* eprow = ep + row * 260;
          #pragma unroll
          for (int nf = 0; nf < 4; ++nf) {
            const int col = wc * 64 + nf * 16 + (lane & 15);
            eprow[col] = acc[mb + mfl][nf][j] + b2v[nf];
          }
        }
      }
    }
    __syncthreads();

    float o[32];
    #pragma unroll
    for (int k = 0; k < 8; ++k) {
      f32x4 v = *(const f32x4*)(ep + r * 260 + g * 32 + 4 * k);
      o[4 * k + 0] = v[0]; o[4 * k + 1] = v[1];
      o[4 * k + 2] = v[2]; o[4 * k + 3] = v[3];
    }

    const int bidx = m0 + pair * 64 + r;
    const float phi = zin[(size_t)bidx * 1024 + 2 * tglob + 1];
    const float x = tanf(0.5f * (phi - PI_F));
    const float x2p1 = fmaf(x, x, 1.0f);

    float mx = -1e30f;
    #pragma unroll
    for (int e = 0; e < 10; ++e) mx = fmaxf(mx, o[3 * e + 2]);

    float s = 0.f, outv = 0.f, dsum = 0.f;
    #pragma unroll
    for (int e = 0; e < 10; ++e) {
      float re = __expf(o[3 * e + 2] - mx);
      s += re;
      float av = o[3 * e];
      float aa = fmaxf(av, 0.f) + __logf(1.f + __expf(-fabsf(av))) + 0.001f;
      float u = fmaf(aa, x, o[3 * e + 1]);
      outv = fmaf(re, fmaf(2.f, atanf(u), PI_F), outv);
      dsum = fmaf(re, aa * x2p1 / fmaf(u, u, 1.f), dsum);
    }
    float inv = 1.f / s;
    zout[(size_t)bidx * 1024 + 2 * tglob + 1] = outv * inv;
    ldp[g * 68 + r] = __logf(dsum * inv);

    __syncthreads();
    if (tid < 64) {
      float sld = 0.f;
      #pragma unroll
      for (int gg = 0; gg < 8; ++gg) sld += ldp[gg * 68 + tid];
      atomicAdd(&logdet[m0 + pair * 64 + tid], sld);
    }
  }
}

// ---------------------------------------------------------------------------
extern "C" void kernel_launch(void* const* d_in, const int* in_sizes, int n_in,
                              void* d_out, int out_size, void* d_ws, size_t ws_size,
                              hipStream_t stream) {
  const float* z  = (const float*)d_in[0];
  const float* W1 = (const float*)d_in[1];
  const float* b1 = (const float*)d_in[2];
  const float* W2 = (const float*)d_in[3];
  const float* b2 = (const float*)d_in[4];

  float* zout   = (float*)d_out;               // 8192*1024
  float* logdet = zout + (size_t)8192 * 1024;  // 8192

  // ws layout (64 MiB): hB 0..16M, W1T 16..18M, featB 32..48M (dead after
  // gemm1), W2Tp 32..64M (written after gemm1, overlays featB).
  char* ws = (char*)d_ws;
  __hip_bfloat16* hB    = (__hip_bfloat16*)ws;
  __hip_bfloat16* W1T   = (__hip_bfloat16*)(ws + 16777216);
  __hip_bfloat16* featB = (__hip_bfloat16*)(ws + 33554432);
  __hip_bfloat16* W2Tp  = (__hip_bfloat16*)(ws + 33554432);

  prep_feat_kernel<<<16384, 256, 0, stream>>>(z, featB, zout, logdet);
  transpose_bf16_kernel<<<dim3(32, 32), dim3(32, 8), 0, stream>>>(W1, W1T, 1024, 1024);
  gemm1_kernel<<<dim3(64, 8), 256, 0, stream>>>(featB, W1T, b1, hB);
  transpose_w2_pad_kernel<<<dim3(512, 32), dim3(32, 8), 0, stream>>>(W2, W2Tp);
  gemm2_ncp_kernel<<<dim3(32, 64), 512, 0, stream>>>(hB, W2Tp, b2, z, zout, logdet);
}